// Round 7
// baseline (667.482 us; speedup 1.0000x reference)
//
#include <hip/hip_runtime.h>
#include <stdint.h>

// SparseAttentionAggregator: B=4 H=16 S=2048 D=64, fp32 in/out, mask [B,S,S] int32
// out = softmax((Q K^T)/8 masked_fill(mask==0,-1e9)) V
//
// R16 = R14 shell (g=2, 4 waves, grid 1024, LDS 33280B, measured 103us) with
// the inner kt-loop restructured into batched phases:
//   P0: all 16 K/V frag ds_reads + 4x2 LUT reads
//   P1: all 16 QK mfma in one setprio(1) cluster (8 indep chains of 2)
//   P2: all 32 exp2 + 16 pack/mask at prio 0 (pure VALU batch)
//   P3: all 20 PV mfma in a second setprio(1) cluster
// Theory (R14/R15 counters): pipes don't overlap -- LDS 50% + MFMA 36% +
// VALU 10% ~ 96% serial. R15 halved LDS share but fell to 2 waves/SIMD ->
// latency-exposed wash. Batching creates long role-distinct bursts so the
// 4 waves/SIMD (from 4 different blocks) can interleave: one wave's VALU
// batch under another's MFMA cluster (T5 mechanism needs this role split).
// Invariants kept: LDS > 32KB (R13 lesson), VGPR free under bounds(256,4)
// (R11 lesson), h-innermost XCD pinning, gload_lds dbuf, osum on MFMA pipe.
// prep v2 (LDS-bounce) + byte-pack mask unchanged.

#define SQ 2048
#define DD 64

typedef __attribute__((ext_vector_type(8))) short short8;   // 8 bf16
typedef __attribute__((ext_vector_type(4))) short bshort4;  // 4 bf16
typedef __attribute__((ext_vector_type(4))) float f32x4;

union U8 { uint32_t u[4]; short8 s; };
union U4 { uint32_t u[2]; bshort4 s; };

__device__ __forceinline__ uint32_t pk_rne(float lo, float hi) {
  uint32_t a = __builtin_bit_cast(uint32_t, lo) + 0x8000u;
  uint32_t b = __builtin_bit_cast(uint32_t, hi) + 0x8000u;
  return __builtin_amdgcn_perm(b, a, 0x07060302u);
}
__device__ __forceinline__ uint32_t pk_tr(float lo, float hi) {
  return __builtin_amdgcn_perm(__builtin_bit_cast(uint32_t, hi),
                               __builtin_bit_cast(uint32_t, lo), 0x07060302u);
}

#if __has_builtin(__builtin_amdgcn_exp2f)
#define EXP2(x) __builtin_amdgcn_exp2f(x)
#else
#define EXP2(x) __exp2f(x)
#endif

__device__ __forceinline__ f32x4 mfma32(short8 a, short8 b, f32x4 c) {
  return __builtin_amdgcn_mfma_f32_16x16x32_bf16(a, b, c, 0, 0, 0);
}
#if __has_builtin(__builtin_amdgcn_mfma_f32_16x16x16bf16_1k)
__device__ __forceinline__ f32x4 mfma16(bshort4 a, bshort4 b, f32x4 c) {
  return __builtin_amdgcn_mfma_f32_16x16x16bf16_1k(a, b, c, 0, 0, 0);
}
#else
__device__ __forceinline__ f32x4 mfma16(bshort4 a, bshort4 b, f32x4 c) {
  asm("v_mfma_f32_16x16x16_bf16 %0, %1, %2, %0" : "+v"(c) : "v"(a), "v"(b));
  return c;
}
#endif

// async 16B/lane global->LDS; dest = base + lane*16
__device__ __forceinline__ void gload_lds16(const short* g, short* l) {
  __builtin_amdgcn_global_load_lds(
      (const __attribute__((address_space(1))) uint32_t*)g,
      (__attribute__((address_space(3))) uint32_t*)l, 16, 0, 0);
}

#define LSTR 66  // padded LDS row stride (floats)

// ---- fused prep v2 ----
// blocks [0,2048):     K-prep, one block per (bh, kt) 64-key tile, LDS-bounce
// blocks [2048,4096):  V-prep, same
// blocks [4096,6144):  mask pack (byte-per-lane, int4 reads)
__global__ __launch_bounds__(256) void prep_all_kernel(
    const float* __restrict__ K, const float* __restrict__ V,
    const int* __restrict__ M, short* __restrict__ Kt,
    short* __restrict__ Vt, uint32_t* __restrict__ bits) {
  __shared__ float sT[64 * LSTR];  // 16.9 KB
  const int bid = blockIdx.x;
  const int t = threadIdx.x;

  if (bid < 4096) {
    const int tile = bid & 2047;                 // (bh, kt)
    const bool isK = bid < 2048;
    const float* src = (isK ? K : V) +
                       (size_t)(tile >> 5) * (SQ * DD) + (size_t)(tile & 31) * 4096;
    // coalesced stage: 8 passes x (8 rows x 64 floats), float2 per lane
#pragma unroll
    for (int p = 0; p < 8; ++p) {
      int row = (t >> 5) + p * 8;
      int c2 = (t & 31) * 2;
      float2 v = *(const float2*)(src + row * 64 + c2);
      sT[row * LSTR + c2] = v.x;
      sT[row * LSTR + c2 + 1] = v.y;
    }
    __syncthreads();

    const int l = t & 63;
    if (isK) {
      // fragment emit: chunks rk = t>>6 and (t>>6)+4
      short* dst = Kt + (size_t)tile * 4096;
#pragma unroll
      for (int half8 = 0; half8 < 2; ++half8) {
        int rk = (t >> 6) + half8 * 4;
        int group = rk >> 2, sub = (rk >> 1) & 1, half = rk & 1;
        int i = l & 15;
        int keyl = group * 32 + (i >> 2) * 8 + sub * 4 + (i & 3);
        int d0 = half * 32 + (l >> 4) * 8;
        const float* s = &sT[keyl * LSTR + d0];
        U8 w;
        w.u[0] = pk_rne(s[0], s[1]); w.u[1] = pk_rne(s[2], s[3]);
        w.u[2] = pk_rne(s[4], s[5]); w.u[3] = pk_rne(s[6], s[7]);
        *(short8*)(dst + (rk * 64 + l) * 8) = w.s;
      }
    } else {
      // V^T fragment emit: chunks rv = t>>6 and (t>>6)+4
      short* dst = Vt + (size_t)tile * 4096;
#pragma unroll
      for (int half8 = 0; half8 < 2; ++half8) {
        int rv = (t >> 6) + half8 * 4;
        int group = rv >> 2, dc = rv & 3;
        int d = dc * 16 + (l & 15);
        int k0 = group * 32 + (l >> 4) * 8;
        const float* s = &sT[k0 * LSTR + d];
        U8 w;
        w.u[0] = pk_rne(s[0 * LSTR], s[1 * LSTR]);
        w.u[1] = pk_rne(s[2 * LSTR], s[3 * LSTR]);
        w.u[2] = pk_rne(s[4 * LSTR], s[5 * LSTR]);
        w.u[3] = pk_rne(s[6 * LSTR], s[7 * LSTR]);
        *(short8*)(dst + (rv * 64 + l) * 8) = w.s;
      }
    }
  } else {
    // ---- mask bits: lane packs 8 ints -> 1 byte; 512 ints/wave/iter ----
    const int lane = t & 63;
    const int gwid = ((bid - 4096) * 256 + t) >> 6;  // 0..8191
    const size_t total = (size_t)4 * SQ * SQ;        // 16,777,216 ints
    for (size_t base = (size_t)gwid * 512; base < total;
         base += (size_t)8192 * 512) {
      const int4* p = (const int4*)(M + base + (size_t)lane * 8);
      int4 a = p[0], b = p[1];
      uint32_t by = (uint32_t)(a.x != 0) | ((uint32_t)(a.y != 0) << 1) |
                    ((uint32_t)(a.z != 0) << 2) | ((uint32_t)(a.w != 0) << 3) |
                    ((uint32_t)(b.x != 0) << 4) | ((uint32_t)(b.y != 0) << 5) |
                    ((uint32_t)(b.z != 0) << 6) | ((uint32_t)(b.w != 0) << 7);
      ((uint8_t*)bits)[(base >> 3) + lane] = (uint8_t)by;
    }
  }
}

// ---- standalone prep kernel (fallback path) ----
__global__ __launch_bounds__(256) void pack_mask_kernel(const int* __restrict__ m,
                                                        uint32_t* __restrict__ bits) {
  const int lane = threadIdx.x & 63;
  const int wid = (blockIdx.x * 256 + threadIdx.x) >> 6;
  const int nw = (gridDim.x * 256) >> 6;
  const size_t total = (size_t)4 * SQ * SQ;
  for (size_t base = (size_t)wid * 64; base < total; base += (size_t)nw * 64) {
    int v = m[base + lane];
    unsigned long long b = __ballot(v != 0);
    if (lane == 0) *(unsigned long long*)&bits[base >> 5] = b;
  }
}

// ---- fast attention: g=2, grid 1024, batched-phase inner loop ----
__global__ __launch_bounds__(256, 4) void attn_fast(
    const float* __restrict__ Qg, const short* __restrict__ Kt,
    const short* __restrict__ Vt, const uint32_t* __restrict__ bits,
    float* __restrict__ Og) {
  __shared__ __align__(16) short sK[2][4096];  // 8KB per buf, fragment order
  __shared__ __align__(16) short sV[2][4096];
  __shared__ __align__(8) uint32_t sLut[32];   // 16 x {m_lo, m_hi}; keeps LDS >32KB

  const int tid = threadIdx.x;
  const int lane = tid & 63;
  const int wv = tid >> 6;
  const int l15 = lane & 15;
  const int quad = lane >> 4;

  const int bid = blockIdx.x;  // (b, qt, h), h innermost -> head pinned to XCD h%8
  const int h = bid & 15;
  const int qt = (bid >> 4) & 15;
  const int b = bid >> 8;

  if (tid < 16) {  // mask LUT: bit r of index -> 0xFFFF half-mask
    uint32_t m0 = ((tid & 1) ? 0xFFFFu : 0u) | ((tid & 2) ? 0xFFFF0000u : 0u);
    uint32_t m1 = ((tid & 4) ? 0xFFFFu : 0u) | ((tid & 8) ? 0xFFFF0000u : 0u);
    sLut[tid * 2] = m0;
    sLut[tid * 2 + 1] = m1;
  }

  const size_t bh = (size_t)b * 16 + h;
  const float* Qp = Qg + bh * (size_t)(SQ * DD);
  const short* Kh = Kt + bh * (size_t)(SQ * DD);
  const short* Vh = Vt + bh * (size_t)(SQ * DD);
  float* Op = Og + bh * (size_t)(SQ * DD);
  const int q0w = qt * 128 + wv * 32;  // 32 q-rows/wave (2 groups)
  const int brow = b * SQ;

  const float QS = 0.18033688f;   // 0.125 * log2(e)
  const float NC = -17.312340f;   // -12 * log2(e)
  const f32x4 NCv = {NC, NC, NC, NC};

  U8 ones8u;
  ones8u.u[0] = 0x3f803f80u; ones8u.u[1] = 0x3f803f80u;
  ones8u.u[2] = 0x3f803f80u; ones8u.u[3] = 0x3f803f80u;
  const short8 ones8 = ones8u.s;

  // Q fragments (pre-scaled); A-layout content (m=l15, k=quad*8+j)
  short8 qf[2][2];
#pragma unroll
  for (int g = 0; g < 2; ++g)
#pragma unroll
    for (int dc = 0; dc < 2; ++dc) {
      const float* src = Qp + (size_t)(q0w + g * 16 + l15) * DD + dc * 32 + quad * 8;
      float4 a = *(const float4*)src;
      float4 c = *(const float4*)(src + 4);
      U8 t;
      t.u[0] = pk_rne(a.x * QS, a.y * QS);
      t.u[1] = pk_rne(a.z * QS, a.w * QS);
      t.u[2] = pk_rne(c.x * QS, c.y * QS);
      t.u[3] = pk_rne(c.z * QS, c.w * QS);
      qf[g][dc] = t.s;
    }

  f32x4 o[2][4];
  f32x4 osum[2];
#pragma unroll
  for (int g = 0; g < 2; ++g) {
#pragma unroll
    for (int dc = 0; dc < 4; ++dc) o[g][dc] = (f32x4){0.f, 0.f, 0.f, 0.f};
    osum[g] = (f32x4){0.f, 0.f, 0.f, 0.f};
  }

  // per-wave staging: 2 K-chunks + 2 V-chunks
  const int rk0 = wv * 2, rk1 = wv * 2 + 1;
  const short* kg0 = Kh + rk0 * 512 + lane * 8;  // +kt*4096 per tile
  const short* kg1 = Kh + rk1 * 512 + lane * 8;
  const short* vg0 = Vh + rk0 * 512 + lane * 8;
  const short* vg1 = Vh + rk1 * 512 + lane * 8;

  uint2 mwc[2], mwn[2];
#pragma unroll
  for (int g = 0; g < 2; ++g)
    mwc[g] = *(const uint2*)&bits[(size_t)(brow + q0w + g * 16 + l15) * (SQ / 32)];

  // prologue: stage tile 0 into buf 0
  gload_lds16(kg0, &sK[0][rk0 * 512]);
  gload_lds16(kg1, &sK[0][rk1 * 512]);
  gload_lds16(vg0, &sV[0][rk0 * 512]);
  gload_lds16(vg1, &sV[0][rk1 * 512]);

  const int shA = quad * 8;       // sub-A keys quad*8+{0..3}
  const int shB = quad * 8 + 4;   // sub-B keys quad*8+{4..7}

  for (int kt = 0; kt < SQ / 64; ++kt) {
    const int buf = kt & 1;

    __syncthreads();  // buf loads complete; buf^1 readers done; sLut visible

    if (kt + 1 < SQ / 64) {  // async-stage next tile into buf^1
      const int off = (kt + 1) * 4096;
      gload_lds16(kg0 + off, &sK[buf ^ 1][rk0 * 512]);
      gload_lds16(kg1 + off, &sK[buf ^ 1][rk1 * 512]);
      gload_lds16(vg0 + off, &sV[buf ^ 1][rk0 * 512]);
      gload_lds16(vg1 + off, &sV[buf ^ 1][rk1 * 512]);
#pragma unroll
      for (int g = 0; g < 2; ++g)
        mwn[g] = *(const uint2*)&bits[(size_t)(brow + q0w + g * 16 + l15) * (SQ / 32) + (kt + 1) * 2];
    }

    const short* kb_base = &sK[buf][lane * 8];   // ds_read_b128 imm offsets
    const short* vb_base = &sV[buf][lane * 8];

    // ---- P0: batched frag + LUT loads ----
    short8 kf[2][4], vf[2][4];
#pragma unroll
    for (int grp = 0; grp < 2; ++grp)
#pragma unroll
      for (int r = 0; r < 4; ++r) {
        kf[grp][r] = *(const short8*)&kb_base[(grp * 4 + r) * 512];
        vf[grp][r] = *(const short8*)&vb_base[(grp * 4 + r) * 512];
      }
    uint2 mskA[2][2], mskB[2][2];
#pragma unroll
    for (int grp = 0; grp < 2; ++grp)
#pragma unroll
      for (int g = 0; g < 2; ++g) {
        uint32_t w = grp ? mwc[g].y : mwc[g].x;
        mskA[grp][g] = *(const uint2*)&sLut[((w >> shA) & 15u) * 2];
        mskB[grp][g] = *(const uint2*)&sLut[((w >> shB) & 15u) * 2];
      }

    // ---- P1: all QK mfma (8 indep chains of 2) ----
    f32x4 stA[2][2], stB[2][2];
    __builtin_amdgcn_s_setprio(1);
#pragma unroll
    for (int grp = 0; grp < 2; ++grp)
#pragma unroll
      for (int g = 0; g < 2; ++g) {
        f32x4 ta = mfma32(kf[grp][0], qf[g][0], NCv);
        stA[grp][g] = mfma32(kf[grp][1], qf[g][1], ta);
        f32x4 tb = mfma32(kf[grp][2], qf[g][0], NCv);
        stB[grp][g] = mfma32(kf[grp][3], qf[g][1], tb);
      }
    __builtin_amdgcn_s_setprio(0);

    // ---- P2: all exp2 + pack + mask (VALU batch) ----
    U8 pw[2][2];
#pragma unroll
    for (int grp = 0; grp < 2; ++grp)
#pragma unroll
      for (int g = 0; g < 2; ++g) {
        float pA0 = EXP2(stA[grp][g][0]), pA1 = EXP2(stA[grp][g][1]);
        float pA2 = EXP2(stA[grp][g][2]), pA3 = EXP2(stA[grp][g][3]);
        float pB0 = EXP2(stB[grp][g][0]), pB1 = EXP2(stB[grp][g][1]);
        float pB2 = EXP2(stB[grp][g][2]), pB3 = EXP2(stB[grp][g][3]);
        pw[grp][g].u[0] = pk_tr(pA0, pA1) & mskA[grp][g].x;
        pw[grp][g].u[1] = pk_tr(pA2, pA3) & mskA[grp][g].y;
        pw[grp][g].u[2] = pk_tr(pB0, pB1) & mskB[grp][g].x;
        pw[grp][g].u[3] = pk_tr(pB2, pB3) & mskB[grp][g].y;
      }

    // ---- P3: all PV mfma (10 chains of 2) ----
    __builtin_amdgcn_s_setprio(1);
#pragma unroll
    for (int grp = 0; grp < 2; ++grp)
#pragma unroll
      for (int g = 0; g < 2; ++g) {
#pragma unroll
        for (int dc = 0; dc < 4; ++dc)
          o[g][dc] = mfma32(pw[grp][g].s, vf[grp][dc], o[g][dc]);
        osum[g] = mfma32(pw[grp][g].s, ones8, osum[g]);  // row sums on MFMA pipe
      }
    __builtin_amdgcn_s_setprio(0);

    if (kt + 1 < SQ / 64) {
#pragma unroll
      for (int g = 0; g < 2; ++g) mwc[g] = mwn[g];
    }
  }

  // epilogue: osum C/D layout == store layout; no shuffles
#pragma unroll
  for (int g = 0; g < 2; ++g)
#pragma unroll
    for (int r = 0; r < 4; ++r) {
      float inv = 1.0f / osum[g][r];
      float* dst = Op + (size_t)(q0w + g * 16 + quad * 4 + r) * DD + l15;
      dst[0]  = o[g][0][r] * inv;
      dst[16] = o[g][1][r] * inv;
      dst[32] = o[g][2][r] * inv;
      dst[48] = o[g][3][r] * inv;
    }
}

// ---- fallback (R3-winning structure) for small ws ----
template <bool USE_BITS>
__global__ __launch_bounds__(256, 2) void attn_fb(
    const float* __restrict__ Qg, const float* __restrict__ Kg,
    const float* __restrict__ Vg, const int* __restrict__ Mg,
    const uint32_t* __restrict__ bits, float* __restrict__ Og) {
  __shared__ __align__(16) short sK[2][64 * 72];
  __shared__ __align__(16) short sVT[2][64 * 72];
  const int tid = threadIdx.x;
  const int lane = tid & 63;
  const int wv = tid >> 6;
  const int l15 = lane & 15;
  const int quad = lane >> 4;
  const int bid = blockIdx.x;
  const int h = bid & 15;
  const int qt = (bid >> 4) & 7;
  const int b = bid >> 7;
  const size_t bh = (size_t)b * 16 + h;
  const float* Qp = Qg + bh * (size_t)(SQ * DD);
  const float* Kp = Kg + bh * (size_t)(SQ * DD);
  const float* Vp = Vg + bh * (size_t)(SQ * DD);
  float* Op = Og + bh * (size_t)(SQ * DD);
  const int q0w = qt * 256 + wv * 64;
  const int brow = b * SQ;
  const float QS = 0.18033688f, NC = -17.312340f;
  const float NINF = -__builtin_inff();
  U4 onesu; onesu.u[0] = 0x3f803f80u; onesu.u[1] = 0x3f803f80u;
  const bshort4 ones = onesu.s;
  short8 qf[4][2];
#pragma unroll
  for (int g = 0; g < 4; ++g)
#pragma unroll
    for (int dc = 0; dc < 2; ++dc) {
      const float* src = Qp + (size_t)(q0w + g * 16 + l15) * DD + dc * 32 + quad * 8;
      float4 a = *(const float4*)src;
      float4 c = *(const float4*)(src + 4);
      U8 t;
      t.u[0] = pk_rne(a.x * QS, a.y * QS); t.u[1] = pk_rne(a.z * QS, a.w * QS);
      t.u[2] = pk_rne(c.x * QS, c.y * QS); t.u[3] = pk_rne(c.z * QS, c.w * QS);
      qf[g][dc] = t.s;
    }
  f32x4 o[4][4]; f32x4 osum[4];
#pragma unroll
  for (int g = 0; g < 4; ++g) {
#pragma unroll
    for (int dc = 0; dc < 4; ++dc) o[g][dc] = (f32x4){0.f, 0.f, 0.f, 0.f};
    osum[g] = (f32x4){0.f, 0.f, 0.f, 0.f};
  }
  const int kr = lane, kcb = wv * 16;
  const int vr2 = (lane & 31) * 2, vcb = wv * 16 + (lane >> 5) * 8;
  const float* kbase = Kp + (size_t)kr * DD + kcb;
  const float* vbase = Vp + (size_t)vr2 * DD + vcb;
  float4 kA, kB, kC, kD, vA, vB, vC, vD;
  uint2 mwc[4], mwn[4];
  {
    const float4* kp = (const float4*)kbase;
    kA = kp[0]; kB = kp[1]; kC = kp[2]; kD = kp[3];
    const float* r0 = vbase;
    vA = ((const float4*)r0)[0]; vB = ((const float4*)r0)[1];
    vC = ((const float4*)(r0 + DD))[0]; vD = ((const float4*)(r0 + DD))[1];
    if (USE_BITS) {
#pragma unroll
      for (int g = 0; g < 4; ++g)
        mwc[g] = *(const uint2*)&bits[(size_t)(brow + q0w + g * 16 + l15) * (SQ / 32)];
    }
    U8 w0, w1;
    w0.u[0] = pk_rne(kA.x, kA.y); w0.u[1] = pk_rne(kA.z, kA.w);
    w0.u[2] = pk_rne(kB.x, kB.y); w0.u[3] = pk_rne(kB.z, kB.w);
    w1.u[0] = pk_rne(kC.x, kC.y); w1.u[1] = pk_rne(kC.z, kC.w);
    w1.u[2] = pk_rne(kD.x, kD.y); w1.u[3] = pk_rne(kD.z, kD.w);
    *(short8*)&sK[0][kr * 72 + kcb] = w0.s;
    *(short8*)&sK[0][kr * 72 + kcb + 8] = w1.s;
    float av[8] = {vA.x, vA.y, vA.z, vA.w, vB.x, vB.y, vB.z, vB.w};
    float bv[8] = {vC.x, vC.y, vC.z, vC.w, vD.x, vD.y, vD.z, vD.w};
#pragma unroll
    for (int j = 0; j < 8; ++j)
      *(uint32_t*)&sVT[0][(vcb + j) * 72 + vr2] = pk_rne(av[j], bv[j]);
  }
  for (int kt = 0; kt < SQ / 64; ++kt) {
    const int buf = kt & 1;
    const int k0 = kt * 64;
    __syncthreads();
    if (kt + 1 < SQ / 64) {
      const float4* kp = (const float4*)(kbase + (size_t)(k0 + 64) * DD);
      kA = kp[0]; kB = kp[1]; kC = kp[2]; kD = kp[3];
      const float* r0 = vbase + (size_t)(k0 + 64) * DD;
      vA = ((const float4*)r0)[0]; vB = ((const float4*)r0)[1];
      vC = ((const float4*)(r0 + DD))[0]; vD = ((const float4*)(r0 + DD))[1];
      if (USE_BITS) {
#pragma unroll
        for (int g = 0; g < 4; ++g)
          mwn[g] = *(const uint2*)&bits[(size_t)(brow + q0w + g * 16 + l15) * (SQ / 32) + (kt + 1) * 2];
      }
    }
    const short* sKb = sK[buf];
    const short* sVb = sVT[buf];
#pragma unroll
    for (int kb = 0; kb < 4; ++kb) {
      short8 kfa = *(const short8*)&sKb[(kb * 16 + l15) * 72 + quad * 8];
      short8 kfb = *(const short8*)&sKb[(kb * 16 + l15) * 72 + 32 + quad * 8];
      bshort4 vf[4];
#pragma unroll
      for (int dc = 0; dc < 4; ++dc)
        vf[dc] = *(const bshort4*)&sVb[(dc * 16 + l15) * 72 + kb * 16 + quad * 4];
#pragma unroll
      for (int g = 0; g < 4; ++g) {
        uint32_t t;
        if (USE_BITS) {
          uint32_t w = (kb & 2) ? mwc[g].y : mwc[g].x;
          t = w >> ((kb & 1) * 16 + quad * 4);
        } else {
          const int* mrow = Mg + (size_t)(brow + q0w + g * 16 + l15) * SQ + k0 + kb * 16 + quad * 4;
          t = (mrow[0] != 0) | ((mrow[1] != 0) << 1) | ((mrow[2] != 0) << 2) |
              ((mrow[3] != 0) << 3);
        }
        f32x4 ci;
        ci[0] = (t & 1) ? NC : NINF;
        ci[1] = (t & 2) ? NC : NINF;
        ci[2] = (t & 4) ? NC : NINF;
        ci[3] = (t & 8) ? NC : NINF;
        f32x4 st = mfma32(kfa, qf[g][0], ci);
        st = mfma32(kfb, qf[g][1], st);
        float p0 = EXP2(st[0]), p1 = EXP2(st[1]), p2 = EXP2(st[2]), p3 = EXP2(st[3]);
        U4 pw;
        pw.u[0] = pk_tr(p0, p1);
        pw.u[1] = pk_tr(p2, p3);
#pragma unroll
        for (int dc = 0; dc < 4; ++dc)
          o[g][dc] = mfma16(pw.s, vf[dc], o[g][dc]);
        osum[g] = mfma16(pw.s, ones, osum[g]);
      }
    }
    if (kt + 1 < SQ / 64) {
      short* dK = (short*)sK[buf ^ 1];
      short* dV = (short*)sVT[buf ^ 1];
      U8 w0, w1;
      w0.u[0] = pk_rne(kA.x, kA.y); w0.u[1] = pk_rne(kA.z, kA.w);
      w0.u[2] = pk_rne(kB.x, kB.y); w0.u[3] = pk_rne(kB.z, kB.w);
      w1.u[0] = pk_rne(kC.x, kC.y); w1.u[1] = pk_rne(kC.z, kC.w);
      w1.u[2] = pk_rne(kD.x, kD.y); w1.u[3] = pk_rne(kD.z, kD.w);
      *(short8*)&dK[kr * 72 + kcb] = w0.s;
      *(short8*)&dK[kr * 72 + kcb + 8] = w1.s;
      float av[8] = {vA.x, vA.y, vA.z, vA.w, vB.x, vB.y, vB.z, vB.w};
      float bv[8] = {vC.x, vC.y, vC.z, vC.w, vD.x, vD.y, vD.z, vD.w};
#pragma unroll
      for (int j = 0; j < 8; ++j)
        *(uint32_t*)&dV[(vcb + j) * 72 + vr2] = pk_rne(av[j], bv[j]);
      if (USE_BITS) {
#pragma unroll
        for (int g = 0; g < 4; ++g) mwc[g] = mwn[g];
      }
    }
  }
#pragma unroll
  for (int g = 0; g < 4; ++g)
#pragma unroll
    for (int r = 0; r < 4; ++r) {
      float inv = 1.0f / osum[g][r];
      float* dst = Op + (size_t)(q0w + g * 16 + quad * 4 + r) * DD + l15;
      dst[0]  = o[g][0][r] * inv;
      dst[16] = o[g][1][r] * inv;
      dst[32] = o[g][2][r] * inv;
      dst[48] = o[g][3][r] * inv;
    }
}

extern "C" void kernel_launch(void* const* d_in, const int* in_sizes, int n_in,
                              void* d_out, int out_size, void* d_ws, size_t ws_size,
                              hipStream_t stream) {
  const float* Q = (const float*)d_in[0];
  const float* K = (const float*)d_in[1];
  const float* V = (const float*)d_in[2];
  const int* M = (const int*)d_in[3];
  float* out = (float*)d_out;

  const size_t bits_bytes = (size_t)4 * SQ * SQ / 8;          // 2 MB
  const size_t kv_bytes = (size_t)64 * SQ * DD * 2;           // 16.78 MB each
  const size_t full_bytes = bits_bytes + 2 * kv_bytes;        // 35.65 MB

  if (ws_size >= full_bytes) {
    uint32_t* bits = (uint32_t*)d_ws;
    short* Kt = (short*)((char*)d_ws + bits_bytes);
    short* Vt = (short*)((char*)d_ws + bits_bytes + kv_bytes);
    prep_all_kernel<<<6144, 256, 0, stream>>>(K, V, M, Kt, Vt, bits);
    attn_fast<<<4 * (SQ / 128) * 16, 256, 0, stream>>>(Q, Kt, Vt, bits, out);  // 1024
  } else if (ws_size >= bits_bytes) {
    uint32_t* bits = (uint32_t*)d_ws;
    pack_mask_kernel<<<2048, 256, 0, stream>>>(M, bits);
    attn_fb<true><<<4 * (SQ / 256) * 16, 256, 0, stream>>>(Q, K, V, M, bits, out);
  } else {
    attn_fb<false><<<4 * (SQ / 256) * 16, 256, 0, stream>>>(Q, K, V, M, nullptr, out);
  }
}

// Round 8
// 263.473 us; speedup vs baseline: 2.5334x; 2.5334x over previous
//
#include <hip/hip_runtime.h>
#include <stdint.h>

// SparseAttentionAggregator: B=4 H=16 S=2048 D=64, fp32 in/out, mask [B,S,S] int32
// out = softmax((Q K^T)/8 masked_fill(mask==0,-1e9)) V
//
// R17 = byte-exact revert to the best measured config (R5/R14, 264.59us total,
// attn 103.3us). R16's batched-phase experiment spilled (live set ~170 regs vs
// 128 budget under bounds(256,4) -> 1GB scratch writes -> 523us) and is
// abandoned. Session constraints now locked by measurement:
//  - LDS block size must be in (32KB, 40KB]: exactly 4 blocks/CU uniform
//    packing; below 32KB -> 5-block uneven packing -> L2 thrash (R13: 10x fetch).
//  - Never force occupancy via launch_bounds 2nd arg (R11: VGPR 32 -> spills).
//  - Keep per-iteration live set small (interleaved grp loop, not batched
//    phases): R16 proved batching overflows the register budget.
//  - g=2/4-wave/grid-1024 beats g=4/2-block (R15: latency-exposed at 2w/SIMD).
// attn profile at this config: MFMA 31%, VALU 41%, ~22% stall; structural
// improvements require a 32x32-MFMA relayout (full rewrite, high risk).

#define SQ 2048
#define DD 64

typedef __attribute__((ext_vector_type(8))) short short8;   // 8 bf16
typedef __attribute__((ext_vector_type(4))) short bshort4;  // 4 bf16
typedef __attribute__((ext_vector_type(4))) float f32x4;

union U8 { uint32_t u[4]; short8 s; };
union U4 { uint32_t u[2]; bshort4 s; };

__device__ __forceinline__ uint32_t pk_rne(float lo, float hi) {
  uint32_t a = __builtin_bit_cast(uint32_t, lo) + 0x8000u;
  uint32_t b = __builtin_bit_cast(uint32_t, hi) + 0x8000u;
  return __builtin_amdgcn_perm(b, a, 0x07060302u);
}
__device__ __forceinline__ uint32_t pk_tr(float lo, float hi) {
  return __builtin_amdgcn_perm(__builtin_bit_cast(uint32_t, hi),
                               __builtin_bit_cast(uint32_t, lo), 0x07060302u);
}

#if __has_builtin(__builtin_amdgcn_exp2f)
#define EXP2(x) __builtin_amdgcn_exp2f(x)
#else
#define EXP2(x) __exp2f(x)
#endif

__device__ __forceinline__ f32x4 mfma32(short8 a, short8 b, f32x4 c) {
  return __builtin_amdgcn_mfma_f32_16x16x32_bf16(a, b, c, 0, 0, 0);
}
#if __has_builtin(__builtin_amdgcn_mfma_f32_16x16x16bf16_1k)
__device__ __forceinline__ f32x4 mfma16(bshort4 a, bshort4 b, f32x4 c) {
  return __builtin_amdgcn_mfma_f32_16x16x16bf16_1k(a, b, c, 0, 0, 0);
}
#else
__device__ __forceinline__ f32x4 mfma16(bshort4 a, bshort4 b, f32x4 c) {
  asm("v_mfma_f32_16x16x16_bf16 %0, %1, %2, %0" : "+v"(c) : "v"(a), "v"(b));
  return c;
}
#endif

// async 16B/lane global->LDS; dest = base + lane*16
__device__ __forceinline__ void gload_lds16(const short* g, short* l) {
  __builtin_amdgcn_global_load_lds(
      (const __attribute__((address_space(1))) uint32_t*)g,
      (__attribute__((address_space(3))) uint32_t*)l, 16, 0, 0);
}

#define LSTR 66  // padded LDS row stride (floats)

// ---- fused prep v2 ----
// blocks [0,2048):     K-prep, one block per (bh, kt) 64-key tile, LDS-bounce
// blocks [2048,4096):  V-prep, same
// blocks [4096,6144):  mask pack (byte-per-lane, int4 reads)
__global__ __launch_bounds__(256) void prep_all_kernel(
    const float* __restrict__ K, const float* __restrict__ V,
    const int* __restrict__ M, short* __restrict__ Kt,
    short* __restrict__ Vt, uint32_t* __restrict__ bits) {
  __shared__ float sT[64 * LSTR];  // 16.9 KB
  const int bid = blockIdx.x;
  const int t = threadIdx.x;

  if (bid < 4096) {
    const int tile = bid & 2047;                 // (bh, kt)
    const bool isK = bid < 2048;
    const float* src = (isK ? K : V) +
                       (size_t)(tile >> 5) * (SQ * DD) + (size_t)(tile & 31) * 4096;
    // coalesced stage: 8 passes x (8 rows x 64 floats), float2 per lane
#pragma unroll
    for (int p = 0; p < 8; ++p) {
      int row = (t >> 5) + p * 8;
      int c2 = (t & 31) * 2;
      float2 v = *(const float2*)(src + row * 64 + c2);
      sT[row * LSTR + c2] = v.x;
      sT[row * LSTR + c2 + 1] = v.y;
    }
    __syncthreads();

    const int l = t & 63;
    if (isK) {
      // fragment emit: chunks rk = t>>6 and (t>>6)+4
      short* dst = Kt + (size_t)tile * 4096;
#pragma unroll
      for (int half8 = 0; half8 < 2; ++half8) {
        int rk = (t >> 6) + half8 * 4;
        int group = rk >> 2, sub = (rk >> 1) & 1, half = rk & 1;
        int i = l & 15;
        int keyl = group * 32 + (i >> 2) * 8 + sub * 4 + (i & 3);
        int d0 = half * 32 + (l >> 4) * 8;
        const float* s = &sT[keyl * LSTR + d0];
        U8 w;
        w.u[0] = pk_rne(s[0], s[1]); w.u[1] = pk_rne(s[2], s[3]);
        w.u[2] = pk_rne(s[4], s[5]); w.u[3] = pk_rne(s[6], s[7]);
        *(short8*)(dst + (rk * 64 + l) * 8) = w.s;
      }
    } else {
      // V^T fragment emit: chunks rv = t>>6 and (t>>6)+4
      short* dst = Vt + (size_t)tile * 4096;
#pragma unroll
      for (int half8 = 0; half8 < 2; ++half8) {
        int rv = (t >> 6) + half8 * 4;
        int group = rv >> 2, dc = rv & 3;
        int d = dc * 16 + (l & 15);
        int k0 = group * 32 + (l >> 4) * 8;
        const float* s = &sT[k0 * LSTR + d];
        U8 w;
        w.u[0] = pk_rne(s[0 * LSTR], s[1 * LSTR]);
        w.u[1] = pk_rne(s[2 * LSTR], s[3 * LSTR]);
        w.u[2] = pk_rne(s[4 * LSTR], s[5 * LSTR]);
        w.u[3] = pk_rne(s[6 * LSTR], s[7 * LSTR]);
        *(short8*)(dst + (rv * 64 + l) * 8) = w.s;
      }
    }
  } else {
    // ---- mask bits: lane packs 8 ints -> 1 byte; 512 ints/wave/iter ----
    const int lane = t & 63;
    const int gwid = ((bid - 4096) * 256 + t) >> 6;  // 0..8191
    const size_t total = (size_t)4 * SQ * SQ;        // 16,777,216 ints
    for (size_t base = (size_t)gwid * 512; base < total;
         base += (size_t)8192 * 512) {
      const int4* p = (const int4*)(M + base + (size_t)lane * 8);
      int4 a = p[0], b = p[1];
      uint32_t by = (uint32_t)(a.x != 0) | ((uint32_t)(a.y != 0) << 1) |
                    ((uint32_t)(a.z != 0) << 2) | ((uint32_t)(a.w != 0) << 3) |
                    ((uint32_t)(b.x != 0) << 4) | ((uint32_t)(b.y != 0) << 5) |
                    ((uint32_t)(b.z != 0) << 6) | ((uint32_t)(b.w != 0) << 7);
      ((uint8_t*)bits)[(base >> 3) + lane] = (uint8_t)by;
    }
  }
}

// ---- standalone prep kernel (fallback path) ----
__global__ __launch_bounds__(256) void pack_mask_kernel(const int* __restrict__ m,
                                                        uint32_t* __restrict__ bits) {
  const int lane = threadIdx.x & 63;
  const int wid = (blockIdx.x * 256 + threadIdx.x) >> 6;
  const int nw = (gridDim.x * 256) >> 6;
  const size_t total = (size_t)4 * SQ * SQ;
  for (size_t base = (size_t)wid * 64; base < total; base += (size_t)nw * 64) {
    int v = m[base + lane];
    unsigned long long b = __ballot(v != 0);
    if (lane == 0) *(unsigned long long*)&bits[base >> 5] = b;
  }
}

// ---- fast attention: R10 exact (g=2, grid 1024, sLut, mfma32 PV) ----
__global__ __launch_bounds__(256, 4) void attn_fast(
    const float* __restrict__ Qg, const short* __restrict__ Kt,
    const short* __restrict__ Vt, const uint32_t* __restrict__ bits,
    float* __restrict__ Og) {
  __shared__ __align__(16) short sK[2][4096];  // 8KB per buf, fragment order
  __shared__ __align__(16) short sV[2][4096];
  __shared__ __align__(8) uint32_t sLut[32];   // 16 x {m_lo, m_hi}; keeps LDS >32KB

  const int tid = threadIdx.x;
  const int lane = tid & 63;
  const int wv = tid >> 6;
  const int l15 = lane & 15;
  const int quad = lane >> 4;

  const int bid = blockIdx.x;  // (b, qt, h), h innermost -> head pinned to XCD h%8
  const int h = bid & 15;
  const int qt = (bid >> 4) & 15;
  const int b = bid >> 8;

  if (tid < 16) {  // mask LUT: bit r of index -> 0xFFFF half-mask
    uint32_t m0 = ((tid & 1) ? 0xFFFFu : 0u) | ((tid & 2) ? 0xFFFF0000u : 0u);
    uint32_t m1 = ((tid & 4) ? 0xFFFFu : 0u) | ((tid & 8) ? 0xFFFF0000u : 0u);
    sLut[tid * 2] = m0;
    sLut[tid * 2 + 1] = m1;
  }

  const size_t bh = (size_t)b * 16 + h;
  const float* Qp = Qg + bh * (size_t)(SQ * DD);
  const short* Kh = Kt + bh * (size_t)(SQ * DD);
  const short* Vh = Vt + bh * (size_t)(SQ * DD);
  float* Op = Og + bh * (size_t)(SQ * DD);
  const int q0w = qt * 128 + wv * 32;  // 32 q-rows/wave (2 groups)
  const int brow = b * SQ;

  const float QS = 0.18033688f;   // 0.125 * log2(e)
  const float NC = -17.312340f;   // -12 * log2(e)
  const f32x4 NCv = {NC, NC, NC, NC};

  U8 ones8u;
  ones8u.u[0] = 0x3f803f80u; ones8u.u[1] = 0x3f803f80u;
  ones8u.u[2] = 0x3f803f80u; ones8u.u[3] = 0x3f803f80u;
  const short8 ones8 = ones8u.s;

  // Q fragments (pre-scaled); A-layout content (m=l15, k=quad*8+j)
  short8 qf[2][2];
#pragma unroll
  for (int g = 0; g < 2; ++g)
#pragma unroll
    for (int dc = 0; dc < 2; ++dc) {
      const float* src = Qp + (size_t)(q0w + g * 16 + l15) * DD + dc * 32 + quad * 8;
      float4 a = *(const float4*)src;
      float4 c = *(const float4*)(src + 4);
      U8 t;
      t.u[0] = pk_rne(a.x * QS, a.y * QS);
      t.u[1] = pk_rne(a.z * QS, a.w * QS);
      t.u[2] = pk_rne(c.x * QS, c.y * QS);
      t.u[3] = pk_rne(c.z * QS, c.w * QS);
      qf[g][dc] = t.s;
    }

  f32x4 o[2][4];
  f32x4 osum[2];
#pragma unroll
  for (int g = 0; g < 2; ++g) {
#pragma unroll
    for (int dc = 0; dc < 4; ++dc) o[g][dc] = (f32x4){0.f, 0.f, 0.f, 0.f};
    osum[g] = (f32x4){0.f, 0.f, 0.f, 0.f};
  }

  // per-wave staging: 2 K-chunks + 2 V-chunks
  const int rk0 = wv * 2, rk1 = wv * 2 + 1;
  const short* kg0 = Kh + rk0 * 512 + lane * 8;  // +kt*4096 per tile
  const short* kg1 = Kh + rk1 * 512 + lane * 8;
  const short* vg0 = Vh + rk0 * 512 + lane * 8;
  const short* vg1 = Vh + rk1 * 512 + lane * 8;

  uint2 mwc[2], mwn[2];
#pragma unroll
  for (int g = 0; g < 2; ++g)
    mwc[g] = *(const uint2*)&bits[(size_t)(brow + q0w + g * 16 + l15) * (SQ / 32)];

  // prologue: stage tile 0 into buf 0
  gload_lds16(kg0, &sK[0][rk0 * 512]);
  gload_lds16(kg1, &sK[0][rk1 * 512]);
  gload_lds16(vg0, &sV[0][rk0 * 512]);
  gload_lds16(vg1, &sV[0][rk1 * 512]);

  const int shA = quad * 8;       // sub-A keys quad*8+{0..3}
  const int shB = quad * 8 + 4;   // sub-B keys quad*8+{4..7}

  for (int kt = 0; kt < SQ / 64; ++kt) {
    const int buf = kt & 1;

    __syncthreads();  // buf loads complete; buf^1 readers done; sLut visible

    if (kt + 1 < SQ / 64) {  // async-stage next tile into buf^1
      const int off = (kt + 1) * 4096;
      gload_lds16(kg0 + off, &sK[buf ^ 1][rk0 * 512]);
      gload_lds16(kg1 + off, &sK[buf ^ 1][rk1 * 512]);
      gload_lds16(vg0 + off, &sV[buf ^ 1][rk0 * 512]);
      gload_lds16(vg1 + off, &sV[buf ^ 1][rk1 * 512]);
#pragma unroll
      for (int g = 0; g < 2; ++g)
        mwn[g] = *(const uint2*)&bits[(size_t)(brow + q0w + g * 16 + l15) * (SQ / 32) + (kt + 1) * 2];
    }

    const short* kb_base = &sK[buf][lane * 8];   // ds_read_b128 imm offsets
    const short* vb_base = &sV[buf][lane * 8];

#pragma unroll
    for (int grp = 0; grp < 2; ++grp) {
      short8 kA0 = *(const short8*)&kb_base[(grp * 4 + 0) * 512];
      short8 kA1 = *(const short8*)&kb_base[(grp * 4 + 1) * 512];
      short8 kB0 = *(const short8*)&kb_base[(grp * 4 + 2) * 512];
      short8 kB1 = *(const short8*)&kb_base[(grp * 4 + 3) * 512];
      short8 vf[4];
#pragma unroll
      for (int dc = 0; dc < 4; ++dc)
        vf[dc] = *(const short8*)&vb_base[(grp * 4 + dc) * 512];

#pragma unroll
      for (int g = 0; g < 2; ++g) {
        uint32_t w = grp ? mwc[g].y : mwc[g].x;
        uint32_t tA = (w >> shA) & 15u;
        uint32_t tB = (w >> shB) & 15u;
        uint2 mskA = *(const uint2*)&sLut[tA * 2];  // ds_read_b64
        uint2 mskB = *(const uint2*)&sLut[tB * 2];
        // S^T sub-tiles: stA rows -> keys grp*32+quad*8+{0..3}, stB -> +4
        __builtin_amdgcn_s_setprio(1);             // T5: favor MFMA wave
        f32x4 stA = mfma32(kA0, qf[g][0], NCv);
        stA = mfma32(kA1, qf[g][1], stA);
        f32x4 stB = mfma32(kB0, qf[g][0], NCv);
        stB = mfma32(kB1, qf[g][1], stB);
        __builtin_amdgcn_s_setprio(0);
        float pA0 = EXP2(stA[0]), pA1 = EXP2(stA[1]);
        float pA2 = EXP2(stA[2]), pA3 = EXP2(stA[3]);
        float pB0 = EXP2(stB[0]), pB1 = EXP2(stB[1]);
        float pB2 = EXP2(stB[2]), pB3 = EXP2(stB[3]);
        U8 pw;  // A-layout k=quad*8+j: j0..3 = sub-A, j4..7 = sub-B
        pw.u[0] = pk_tr(pA0, pA1) & mskA.x;
        pw.u[1] = pk_tr(pA2, pA3) & mskA.y;
        pw.u[2] = pk_tr(pB0, pB1) & mskB.x;
        pw.u[3] = pk_tr(pB2, pB3) & mskB.y;
        __builtin_amdgcn_s_setprio(1);             // T5: PV cluster
#pragma unroll
        for (int dc = 0; dc < 4; ++dc)
          o[g][dc] = mfma32(pw.s, vf[dc], o[g][dc]);
        osum[g] = mfma32(pw.s, ones8, osum[g]);  // row sums on MFMA pipe
        __builtin_amdgcn_s_setprio(0);
      }
    }

    if (kt + 1 < SQ / 64) {
#pragma unroll
      for (int g = 0; g < 2; ++g) mwc[g] = mwn[g];
    }
  }

  // epilogue: osum C/D layout == store layout; no shuffles
#pragma unroll
  for (int g = 0; g < 2; ++g)
#pragma unroll
    for (int r = 0; r < 4; ++r) {
      float inv = 1.0f / osum[g][r];
      float* dst = Op + (size_t)(q0w + g * 16 + quad * 4 + r) * DD + l15;
      dst[0]  = o[g][0][r] * inv;
      dst[16] = o[g][1][r] * inv;
      dst[32] = o[g][2][r] * inv;
      dst[48] = o[g][3][r] * inv;
    }
}

// ---- fallback (R3-winning structure) for small ws ----
template <bool USE_BITS>
__global__ __launch_bounds__(256, 2) void attn_fb(
    const float* __restrict__ Qg, const float* __restrict__ Kg,
    const float* __restrict__ Vg, const int* __restrict__ Mg,
    const uint32_t* __restrict__ bits, float* __restrict__ Og) {
  __shared__ __align__(16) short sK[2][64 * 72];
  __shared__ __align__(16) short sVT[2][64 * 72];
  const int tid = threadIdx.x;
  const int lane = tid & 63;
  const int wv = tid >> 6;
  const int l15 = lane & 15;
  const int quad = lane >> 4;
  const int bid = blockIdx.x;
  const int h = bid & 15;
  const int qt = (bid >> 4) & 7;
  const int b = bid >> 7;
  const size_t bh = (size_t)b * 16 + h;
  const float* Qp = Qg + bh * (size_t)(SQ * DD);
  const float* Kp = Kg + bh * (size_t)(SQ * DD);
  const float* Vp = Vg + bh * (size_t)(SQ * DD);
  float* Op = Og + bh * (size_t)(SQ * DD);
  const int q0w = qt * 256 + wv * 64;
  const int brow = b * SQ;
  const float QS = 0.18033688f, NC = -17.312340f;
  const float NINF = -__builtin_inff();
  U4 onesu; onesu.u[0] = 0x3f803f80u; onesu.u[1] = 0x3f803f80u;
  const bshort4 ones = onesu.s;
  short8 qf[4][2];
#pragma unroll
  for (int g = 0; g < 4; ++g)
#pragma unroll
    for (int dc = 0; dc < 2; ++dc) {
      const float* src = Qp + (size_t)(q0w + g * 16 + l15) * DD + dc * 32 + quad * 8;
      float4 a = *(const float4*)src;
      float4 c = *(const float4*)(src + 4);
      U8 t;
      t.u[0] = pk_rne(a.x * QS, a.y * QS); t.u[1] = pk_rne(a.z * QS, a.w * QS);
      t.u[2] = pk_rne(c.x * QS, c.y * QS); t.u[3] = pk_rne(c.z * QS, c.w * QS);
      qf[g][dc] = t.s;
    }
  f32x4 o[4][4]; f32x4 osum[4];
#pragma unroll
  for (int g = 0; g < 4; ++g) {
#pragma unroll
    for (int dc = 0; dc < 4; ++dc) o[g][dc] = (f32x4){0.f, 0.f, 0.f, 0.f};
    osum[g] = (f32x4){0.f, 0.f, 0.f, 0.f};
  }
  const int kr = lane, kcb = wv * 16;
  const int vr2 = (lane & 31) * 2, vcb = wv * 16 + (lane >> 5) * 8;
  const float* kbase = Kp + (size_t)kr * DD + kcb;
  const float* vbase = Vp + (size_t)vr2 * DD + vcb;
  float4 kA, kB, kC, kD, vA, vB, vC, vD;
  uint2 mwc[4], mwn[4];
  {
    const float4* kp = (const float4*)kbase;
    kA = kp[0]; kB = kp[1]; kC = kp[2]; kD = kp[3];
    const float* r0 = vbase;
    vA = ((const float4*)r0)[0]; vB = ((const float4*)r0)[1];
    vC = ((const float4*)(r0 + DD))[0]; vD = ((const float4*)(r0 + DD))[1];
    if (USE_BITS) {
#pragma unroll
      for (int g = 0; g < 4; ++g)
        mwc[g] = *(const uint2*)&bits[(size_t)(brow + q0w + g * 16 + l15) * (SQ / 32)];
    }
    U8 w0, w1;
    w0.u[0] = pk_rne(kA.x, kA.y); w0.u[1] = pk_rne(kA.z, kA.w);
    w0.u[2] = pk_rne(kB.x, kB.y); w0.u[3] = pk_rne(kB.z, kB.w);
    w1.u[0] = pk_rne(kC.x, kC.y); w1.u[1] = pk_rne(kC.z, kC.w);
    w1.u[2] = pk_rne(kD.x, kD.y); w1.u[3] = pk_rne(kD.z, kD.w);
    *(short8*)&sK[0][kr * 72 + kcb] = w0.s;
    *(short8*)&sK[0][kr * 72 + kcb + 8] = w1.s;
    float av[8] = {vA.x, vA.y, vA.z, vA.w, vB.x, vB.y, vB.z, vB.w};
    float bv[8] = {vC.x, vC.y, vC.z, vC.w, vD.x, vD.y, vD.z, vD.w};
#pragma unroll
    for (int j = 0; j < 8; ++j)
      *(uint32_t*)&sVT[0][(vcb + j) * 72 + vr2] = pk_rne(av[j], bv[j]);
  }
  for (int kt = 0; kt < SQ / 64; ++kt) {
    const int buf = kt & 1;
    const int k0 = kt * 64;
    __syncthreads();
    if (kt + 1 < SQ / 64) {
      const float4* kp = (const float4*)(kbase + (size_t)(k0 + 64) * DD);
      kA = kp[0]; kB = kp[1]; kC = kp[2]; kD = kp[3];
      const float* r0 = vbase + (size_t)(k0 + 64) * DD;
      vA = ((const float4*)r0)[0]; vB = ((const float4*)r0)[1];
      vC = ((const float4*)(r0 + DD))[0]; vD = ((const float4*)(r0 + DD))[1];
      if (USE_BITS) {
#pragma unroll
        for (int g = 0; g < 4; ++g)
          mwn[g] = *(const uint2*)&bits[(size_t)(brow + q0w + g * 16 + l15) * (SQ / 32) + (kt + 1) * 2];
      }
    }
    const short* sKb = sK[buf];
    const short* sVb = sVT[buf];
#pragma unroll
    for (int kb = 0; kb < 4; ++kb) {
      short8 kfa = *(const short8*)&sKb[(kb * 16 + l15) * 72 + quad * 8];
      short8 kfb = *(const short8*)&sKb[(kb * 16 + l15) * 72 + 32 + quad * 8];
      bshort4 vf[4];
#pragma unroll
      for (int dc = 0; dc < 4; ++dc)
        vf[dc] = *(const bshort4*)&sVb[(dc * 16 + l15) * 72 + kb * 16 + quad * 4];
#pragma unroll
      for (int g = 0; g < 4; ++g) {
        uint32_t t;
        if (USE_BITS) {
          uint32_t w = (kb & 2) ? mwc[g].y : mwc[g].x;
          t = w >> ((kb & 1) * 16 + quad * 4);
        } else {
          const int* mrow = Mg + (size_t)(brow + q0w + g * 16 + l15) * SQ + k0 + kb * 16 + quad * 4;
          t = (mrow[0] != 0) | ((mrow[1] != 0) << 1) | ((mrow[2] != 0) << 2) |
              ((mrow[3] != 0) << 3);
        }
        f32x4 ci;
        ci[0] = (t & 1) ? NC : NINF;
        ci[1] = (t & 2) ? NC : NINF;
        ci[2] = (t & 4) ? NC : NINF;
        ci[3] = (t & 8) ? NC : NINF;
        f32x4 st = mfma32(kfa, qf[g][0], ci);
        st = mfma32(kfb, qf[g][1], st);
        float p0 = EXP2(st[0]), p1 = EXP2(st[1]), p2 = EXP2(st[2]), p3 = EXP2(st[3]);
        U4 pw;
        pw.u[0] = pk_tr(p0, p1);
        pw.u[1] = pk_tr(p2, p3);
#pragma unroll
        for (int dc = 0; dc < 4; ++dc)
          o[g][dc] = mfma16(pw.s, vf[dc], o[g][dc]);
        osum[g] = mfma16(pw.s, ones, osum[g]);
      }
    }
    if (kt + 1 < SQ / 64) {
      short* dK = (short*)sK[buf ^ 1];
      short* dV = (short*)sVT[buf ^ 1];
      U8 w0, w1;
      w0.u[0] = pk_rne(kA.x, kA.y); w0.u[1] = pk_rne(kA.z, kA.w);
      w0.u[2] = pk_rne(kB.x, kB.y); w0.u[3] = pk_rne(kB.z, kB.w);
      w1.u[0] = pk_rne(kC.x, kC.y); w1.u[1] = pk_rne(kC.z, kC.w);
      w1.u[2] = pk_rne(kD.x, kD.y); w1.u[3] = pk_rne(kD.z, kD.w);
      *(short8*)&dK[kr * 72 + kcb] = w0.s;
      *(short8*)&dK[kr * 72 + kcb + 8] = w1.s;
      float av[8] = {vA.x, vA.y, vA.z, vA.w, vB.x, vB.y, vB.z, vB.w};
      float bv[8] = {vC.x, vC.y, vC.z, vC.w, vD.x, vD.y, vD.z, vD.w};
#pragma unroll
      for (int j = 0; j < 8; ++j)
        *(uint32_t*)&dV[(vcb + j) * 72 + vr2] = pk_rne(av[j], bv[j]);
      if (USE_BITS) {
#pragma unroll
        for (int g = 0; g < 4; ++g) mwc[g] = mwn[g];
      }
    }
  }
#pragma unroll
  for (int g = 0; g < 4; ++g)
#pragma unroll
    for (int r = 0; r < 4; ++r) {
      float inv = 1.0f / osum[g][r];
      float* dst = Op + (size_t)(q0w + g * 16 + quad * 4 + r) * DD + l15;
      dst[0]  = o[g][0][r] * inv;
      dst[16] = o[g][1][r] * inv;
      dst[32] = o[g][2][r] * inv;
      dst[48] = o[g][3][r] * inv;
    }
}

extern "C" void kernel_launch(void* const* d_in, const int* in_sizes, int n_in,
                              void* d_out, int out_size, void* d_ws, size_t ws_size,
                              hipStream_t stream) {
  const float* Q = (const float*)d_in[0];
  const float* K = (const float*)d_in[1];
  const float* V = (const float*)d_in[2];
  const int* M = (const int*)d_in[3];
  float* out = (float*)d_out;

  const size_t bits_bytes = (size_t)4 * SQ * SQ / 8;          // 2 MB
  const size_t kv_bytes = (size_t)64 * SQ * DD * 2;           // 16.78 MB each
  const size_t full_bytes = bits_bytes + 2 * kv_bytes;        // 35.65 MB

  if (ws_size >= full_bytes) {
    uint32_t* bits = (uint32_t*)d_ws;
    short* Kt = (short*)((char*)d_ws + bits_bytes);
    short* Vt = (short*)((char*)d_ws + bits_bytes + kv_bytes);
    prep_all_kernel<<<6144, 256, 0, stream>>>(K, V, M, Kt, Vt, bits);
    attn_fast<<<4 * (SQ / 128) * 16, 256, 0, stream>>>(Q, Kt, Vt, bits, out);  // 1024
  } else if (ws_size >= bits_bytes) {
    uint32_t* bits = (uint32_t*)d_ws;
    pack_mask_kernel<<<2048, 256, 0, stream>>>(M, bits);
    attn_fb<true><<<4 * (SQ / 256) * 16, 256, 0, stream>>>(Q, K, V, M, bits, out);
  } else {
    attn_fb<false><<<4 * (SQ / 256) * 16, 256, 0, stream>>>(Q, K, V, M, nullptr, out);
  }
}

// Round 9
// 260.795 us; speedup vs baseline: 2.5594x; 1.0103x over previous
//
#include <hip/hip_runtime.h>
#include <stdint.h>

// SparseAttentionAggregator: B=4 H=16 S=2048 D=64, fp32 in/out, mask [B,S,S] int32
// out = softmax((Q K^T)/8 masked_fill(mask==0,-1e9)) V
//
// R18 = R17 (best measured 263.5us, attn 103.3) with ONE change: all
// s_setprio calls removed from attn_fast (A/B probe). Setprio was added in
// R10 bundled with prep-fusion, never isolated; catalog data says its sign
// is structure-dependent (+4-7% independent-block attn m191, -1.5% lockstep
// GEMM m190). Ours is hybrid (4-wave barrier-locked blocks, 4 independent
// blocks/CU). Decision rule: attn<101 keep, attn>106 revert, else neutral
// and 263us is the practical plateau (structural rewrite = only headroom).
// All session constraints kept: LDS 33280B in (32KB,40KB] for uniform
// 4-block packing (R13); no forced occupancy bounds (R11); interleaved grp
// loop with small live set (R16); g=2/4-wave/grid-1024 (R15).

#define SQ 2048
#define DD 64

typedef __attribute__((ext_vector_type(8))) short short8;   // 8 bf16
typedef __attribute__((ext_vector_type(4))) short bshort4;  // 4 bf16
typedef __attribute__((ext_vector_type(4))) float f32x4;

union U8 { uint32_t u[4]; short8 s; };
union U4 { uint32_t u[2]; bshort4 s; };

__device__ __forceinline__ uint32_t pk_rne(float lo, float hi) {
  uint32_t a = __builtin_bit_cast(uint32_t, lo) + 0x8000u;
  uint32_t b = __builtin_bit_cast(uint32_t, hi) + 0x8000u;
  return __builtin_amdgcn_perm(b, a, 0x07060302u);
}
__device__ __forceinline__ uint32_t pk_tr(float lo, float hi) {
  return __builtin_amdgcn_perm(__builtin_bit_cast(uint32_t, hi),
                               __builtin_bit_cast(uint32_t, lo), 0x07060302u);
}

#if __has_builtin(__builtin_amdgcn_exp2f)
#define EXP2(x) __builtin_amdgcn_exp2f(x)
#else
#define EXP2(x) __exp2f(x)
#endif

__device__ __forceinline__ f32x4 mfma32(short8 a, short8 b, f32x4 c) {
  return __builtin_amdgcn_mfma_f32_16x16x32_bf16(a, b, c, 0, 0, 0);
}
#if __has_builtin(__builtin_amdgcn_mfma_f32_16x16x16bf16_1k)
__device__ __forceinline__ f32x4 mfma16(bshort4 a, bshort4 b, f32x4 c) {
  return __builtin_amdgcn_mfma_f32_16x16x16bf16_1k(a, b, c, 0, 0, 0);
}
#else
__device__ __forceinline__ f32x4 mfma16(bshort4 a, bshort4 b, f32x4 c) {
  asm("v_mfma_f32_16x16x16_bf16 %0, %1, %2, %0" : "+v"(c) : "v"(a), "v"(b));
  return c;
}
#endif

// async 16B/lane global->LDS; dest = base + lane*16
__device__ __forceinline__ void gload_lds16(const short* g, short* l) {
  __builtin_amdgcn_global_load_lds(
      (const __attribute__((address_space(1))) uint32_t*)g,
      (__attribute__((address_space(3))) uint32_t*)l, 16, 0, 0);
}

#define LSTR 66  // padded LDS row stride (floats)

// ---- fused prep v2 ----
// blocks [0,2048):     K-prep, one block per (bh, kt) 64-key tile, LDS-bounce
// blocks [2048,4096):  V-prep, same
// blocks [4096,6144):  mask pack (byte-per-lane, int4 reads)
__global__ __launch_bounds__(256) void prep_all_kernel(
    const float* __restrict__ K, const float* __restrict__ V,
    const int* __restrict__ M, short* __restrict__ Kt,
    short* __restrict__ Vt, uint32_t* __restrict__ bits) {
  __shared__ float sT[64 * LSTR];  // 16.9 KB
  const int bid = blockIdx.x;
  const int t = threadIdx.x;

  if (bid < 4096) {
    const int tile = bid & 2047;                 // (bh, kt)
    const bool isK = bid < 2048;
    const float* src = (isK ? K : V) +
                       (size_t)(tile >> 5) * (SQ * DD) + (size_t)(tile & 31) * 4096;
    // coalesced stage: 8 passes x (8 rows x 64 floats), float2 per lane
#pragma unroll
    for (int p = 0; p < 8; ++p) {
      int row = (t >> 5) + p * 8;
      int c2 = (t & 31) * 2;
      float2 v = *(const float2*)(src + row * 64 + c2);
      sT[row * LSTR + c2] = v.x;
      sT[row * LSTR + c2 + 1] = v.y;
    }
    __syncthreads();

    const int l = t & 63;
    if (isK) {
      // fragment emit: chunks rk = t>>6 and (t>>6)+4
      short* dst = Kt + (size_t)tile * 4096;
#pragma unroll
      for (int half8 = 0; half8 < 2; ++half8) {
        int rk = (t >> 6) + half8 * 4;
        int group = rk >> 2, sub = (rk >> 1) & 1, half = rk & 1;
        int i = l & 15;
        int keyl = group * 32 + (i >> 2) * 8 + sub * 4 + (i & 3);
        int d0 = half * 32 + (l >> 4) * 8;
        const float* s = &sT[keyl * LSTR + d0];
        U8 w;
        w.u[0] = pk_rne(s[0], s[1]); w.u[1] = pk_rne(s[2], s[3]);
        w.u[2] = pk_rne(s[4], s[5]); w.u[3] = pk_rne(s[6], s[7]);
        *(short8*)(dst + (rk * 64 + l) * 8) = w.s;
      }
    } else {
      // V^T fragment emit: chunks rv = t>>6 and (t>>6)+4
      short* dst = Vt + (size_t)tile * 4096;
#pragma unroll
      for (int half8 = 0; half8 < 2; ++half8) {
        int rv = (t >> 6) + half8 * 4;
        int group = rv >> 2, dc = rv & 3;
        int d = dc * 16 + (l & 15);
        int k0 = group * 32 + (l >> 4) * 8;
        const float* s = &sT[k0 * LSTR + d];
        U8 w;
        w.u[0] = pk_rne(s[0 * LSTR], s[1 * LSTR]);
        w.u[1] = pk_rne(s[2 * LSTR], s[3 * LSTR]);
        w.u[2] = pk_rne(s[4 * LSTR], s[5 * LSTR]);
        w.u[3] = pk_rne(s[6 * LSTR], s[7 * LSTR]);
        *(short8*)(dst + (rv * 64 + l) * 8) = w.s;
      }
    }
  } else {
    // ---- mask bits: lane packs 8 ints -> 1 byte; 512 ints/wave/iter ----
    const int lane = t & 63;
    const int gwid = ((bid - 4096) * 256 + t) >> 6;  // 0..8191
    const size_t total = (size_t)4 * SQ * SQ;        // 16,777,216 ints
    for (size_t base = (size_t)gwid * 512; base < total;
         base += (size_t)8192 * 512) {
      const int4* p = (const int4*)(M + base + (size_t)lane * 8);
      int4 a = p[0], b = p[1];
      uint32_t by = (uint32_t)(a.x != 0) | ((uint32_t)(a.y != 0) << 1) |
                    ((uint32_t)(a.z != 0) << 2) | ((uint32_t)(a.w != 0) << 3) |
                    ((uint32_t)(b.x != 0) << 4) | ((uint32_t)(b.y != 0) << 5) |
                    ((uint32_t)(b.z != 0) << 6) | ((uint32_t)(b.w != 0) << 7);
      ((uint8_t*)bits)[(base >> 3) + lane] = (uint8_t)by;
    }
  }
}

// ---- standalone prep kernel (fallback path) ----
__global__ __launch_bounds__(256) void pack_mask_kernel(const int* __restrict__ m,
                                                        uint32_t* __restrict__ bits) {
  const int lane = threadIdx.x & 63;
  const int wid = (blockIdx.x * 256 + threadIdx.x) >> 6;
  const int nw = (gridDim.x * 256) >> 6;
  const size_t total = (size_t)4 * SQ * SQ;
  for (size_t base = (size_t)wid * 64; base < total; base += (size_t)nw * 64) {
    int v = m[base + lane];
    unsigned long long b = __ballot(v != 0);
    if (lane == 0) *(unsigned long long*)&bits[base >> 5] = b;
  }
}

// ---- fast attention: g=2, grid 1024, sLut, mfma32 PV; NO setprio (A/B) ----
__global__ __launch_bounds__(256, 4) void attn_fast(
    const float* __restrict__ Qg, const short* __restrict__ Kt,
    const short* __restrict__ Vt, const uint32_t* __restrict__ bits,
    float* __restrict__ Og) {
  __shared__ __align__(16) short sK[2][4096];  // 8KB per buf, fragment order
  __shared__ __align__(16) short sV[2][4096];
  __shared__ __align__(8) uint32_t sLut[32];   // 16 x {m_lo, m_hi}; keeps LDS >32KB

  const int tid = threadIdx.x;
  const int lane = tid & 63;
  const int wv = tid >> 6;
  const int l15 = lane & 15;
  const int quad = lane >> 4;

  const int bid = blockIdx.x;  // (b, qt, h), h innermost -> head pinned to XCD h%8
  const int h = bid & 15;
  const int qt = (bid >> 4) & 15;
  const int b = bid >> 8;

  if (tid < 16) {  // mask LUT: bit r of index -> 0xFFFF half-mask
    uint32_t m0 = ((tid & 1) ? 0xFFFFu : 0u) | ((tid & 2) ? 0xFFFF0000u : 0u);
    uint32_t m1 = ((tid & 4) ? 0xFFFFu : 0u) | ((tid & 8) ? 0xFFFF0000u : 0u);
    sLut[tid * 2] = m0;
    sLut[tid * 2 + 1] = m1;
  }

  const size_t bh = (size_t)b * 16 + h;
  const float* Qp = Qg + bh * (size_t)(SQ * DD);
  const short* Kh = Kt + bh * (size_t)(SQ * DD);
  const short* Vh = Vt + bh * (size_t)(SQ * DD);
  float* Op = Og + bh * (size_t)(SQ * DD);
  const int q0w = qt * 128 + wv * 32;  // 32 q-rows/wave (2 groups)
  const int brow = b * SQ;

  const float QS = 0.18033688f;   // 0.125 * log2(e)
  const float NC = -17.312340f;   // -12 * log2(e)
  const f32x4 NCv = {NC, NC, NC, NC};

  U8 ones8u;
  ones8u.u[0] = 0x3f803f80u; ones8u.u[1] = 0x3f803f80u;
  ones8u.u[2] = 0x3f803f80u; ones8u.u[3] = 0x3f803f80u;
  const short8 ones8 = ones8u.s;

  // Q fragments (pre-scaled); A-layout content (m=l15, k=quad*8+j)
  short8 qf[2][2];
#pragma unroll
  for (int g = 0; g < 2; ++g)
#pragma unroll
    for (int dc = 0; dc < 2; ++dc) {
      const float* src = Qp + (size_t)(q0w + g * 16 + l15) * DD + dc * 32 + quad * 8;
      float4 a = *(const float4*)src;
      float4 c = *(const float4*)(src + 4);
      U8 t;
      t.u[0] = pk_rne(a.x * QS, a.y * QS);
      t.u[1] = pk_rne(a.z * QS, a.w * QS);
      t.u[2] = pk_rne(c.x * QS, c.y * QS);
      t.u[3] = pk_rne(c.z * QS, c.w * QS);
      qf[g][dc] = t.s;
    }

  f32x4 o[2][4];
  f32x4 osum[2];
#pragma unroll
  for (int g = 0; g < 2; ++g) {
#pragma unroll
    for (int dc = 0; dc < 4; ++dc) o[g][dc] = (f32x4){0.f, 0.f, 0.f, 0.f};
    osum[g] = (f32x4){0.f, 0.f, 0.f, 0.f};
  }

  // per-wave staging: 2 K-chunks + 2 V-chunks
  const int rk0 = wv * 2, rk1 = wv * 2 + 1;
  const short* kg0 = Kh + rk0 * 512 + lane * 8;  // +kt*4096 per tile
  const short* kg1 = Kh + rk1 * 512 + lane * 8;
  const short* vg0 = Vh + rk0 * 512 + lane * 8;
  const short* vg1 = Vh + rk1 * 512 + lane * 8;

  uint2 mwc[2], mwn[2];
#pragma unroll
  for (int g = 0; g < 2; ++g)
    mwc[g] = *(const uint2*)&bits[(size_t)(brow + q0w + g * 16 + l15) * (SQ / 32)];

  // prologue: stage tile 0 into buf 0
  gload_lds16(kg0, &sK[0][rk0 * 512]);
  gload_lds16(kg1, &sK[0][rk1 * 512]);
  gload_lds16(vg0, &sV[0][rk0 * 512]);
  gload_lds16(vg1, &sV[0][rk1 * 512]);

  const int shA = quad * 8;       // sub-A keys quad*8+{0..3}
  const int shB = quad * 8 + 4;   // sub-B keys quad*8+{4..7}

  for (int kt = 0; kt < SQ / 64; ++kt) {
    const int buf = kt & 1;

    __syncthreads();  // buf loads complete; buf^1 readers done; sLut visible

    if (kt + 1 < SQ / 64) {  // async-stage next tile into buf^1
      const int off = (kt + 1) * 4096;
      gload_lds16(kg0 + off, &sK[buf ^ 1][rk0 * 512]);
      gload_lds16(kg1 + off, &sK[buf ^ 1][rk1 * 512]);
      gload_lds16(vg0 + off, &sV[buf ^ 1][rk0 * 512]);
      gload_lds16(vg1 + off, &sV[buf ^ 1][rk1 * 512]);
#pragma unroll
      for (int g = 0; g < 2; ++g)
        mwn[g] = *(const uint2*)&bits[(size_t)(brow + q0w + g * 16 + l15) * (SQ / 32) + (kt + 1) * 2];
    }

    const short* kb_base = &sK[buf][lane * 8];   // ds_read_b128 imm offsets
    const short* vb_base = &sV[buf][lane * 8];

#pragma unroll
    for (int grp = 0; grp < 2; ++grp) {
      short8 kA0 = *(const short8*)&kb_base[(grp * 4 + 0) * 512];
      short8 kA1 = *(const short8*)&kb_base[(grp * 4 + 1) * 512];
      short8 kB0 = *(const short8*)&kb_base[(grp * 4 + 2) * 512];
      short8 kB1 = *(const short8*)&kb_base[(grp * 4 + 3) * 512];
      short8 vf[4];
#pragma unroll
      for (int dc = 0; dc < 4; ++dc)
        vf[dc] = *(const short8*)&vb_base[(grp * 4 + dc) * 512];

#pragma unroll
      for (int g = 0; g < 2; ++g) {
        uint32_t w = grp ? mwc[g].y : mwc[g].x;
        uint32_t tA = (w >> shA) & 15u;
        uint32_t tB = (w >> shB) & 15u;
        uint2 mskA = *(const uint2*)&sLut[tA * 2];  // ds_read_b64
        uint2 mskB = *(const uint2*)&sLut[tB * 2];
        // S^T sub-tiles: stA rows -> keys grp*32+quad*8+{0..3}, stB -> +4
        f32x4 stA = mfma32(kA0, qf[g][0], NCv);
        stA = mfma32(kA1, qf[g][1], stA);
        f32x4 stB = mfma32(kB0, qf[g][0], NCv);
        stB = mfma32(kB1, qf[g][1], stB);
        float pA0 = EXP2(stA[0]), pA1 = EXP2(stA[1]);
        float pA2 = EXP2(stA[2]), pA3 = EXP2(stA[3]);
        float pB0 = EXP2(stB[0]), pB1 = EXP2(stB[1]);
        float pB2 = EXP2(stB[2]), pB3 = EXP2(stB[3]);
        U8 pw;  // A-layout k=quad*8+j: j0..3 = sub-A, j4..7 = sub-B
        pw.u[0] = pk_tr(pA0, pA1) & mskA.x;
        pw.u[1] = pk_tr(pA2, pA3) & mskA.y;
        pw.u[2] = pk_tr(pB0, pB1) & mskB.x;
        pw.u[3] = pk_tr(pB2, pB3) & mskB.y;
#pragma unroll
        for (int dc = 0; dc < 4; ++dc)
          o[g][dc] = mfma32(pw.s, vf[dc], o[g][dc]);
        osum[g] = mfma32(pw.s, ones8, osum[g]);  // row sums on MFMA pipe
      }
    }

    if (kt + 1 < SQ / 64) {
#pragma unroll
      for (int g = 0; g < 2; ++g) mwc[g] = mwn[g];
    }
  }

  // epilogue: osum C/D layout == store layout; no shuffles
#pragma unroll
  for (int g = 0; g < 2; ++g)
#pragma unroll
    for (int r = 0; r < 4; ++r) {
      float inv = 1.0f / osum[g][r];
      float* dst = Op + (size_t)(q0w + g * 16 + quad * 4 + r) * DD + l15;
      dst[0]  = o[g][0][r] * inv;
      dst[16] = o[g][1][r] * inv;
      dst[32] = o[g][2][r] * inv;
      dst[48] = o[g][3][r] * inv;
    }
}

// ---- fallback (R3-winning structure) for small ws ----
template <bool USE_BITS>
__global__ __launch_bounds__(256, 2) void attn_fb(
    const float* __restrict__ Qg, const float* __restrict__ Kg,
    const float* __restrict__ Vg, const int* __restrict__ Mg,
    const uint32_t* __restrict__ bits, float* __restrict__ Og) {
  __shared__ __align__(16) short sK[2][64 * 72];
  __shared__ __align__(16) short sVT[2][64 * 72];
  const int tid = threadIdx.x;
  const int lane = tid & 63;
  const int wv = tid >> 6;
  const int l15 = lane & 15;
  const int quad = lane >> 4;
  const int bid = blockIdx.x;
  const int h = bid & 15;
  const int qt = (bid >> 4) & 7;
  const int b = bid >> 7;
  const size_t bh = (size_t)b * 16 + h;
  const float* Qp = Qg + bh * (size_t)(SQ * DD);
  const float* Kp = Kg + bh * (size_t)(SQ * DD);
  const float* Vp = Vg + bh * (size_t)(SQ * DD);
  float* Op = Og + bh * (size_t)(SQ * DD);
  const int q0w = qt * 256 + wv * 64;
  const int brow = b * SQ;
  const float QS = 0.18033688f, NC = -17.312340f;
  const float NINF = -__builtin_inff();
  U4 onesu; onesu.u[0] = 0x3f803f80u; onesu.u[1] = 0x3f803f80u;
  const bshort4 ones = onesu.s;
  short8 qf[4][2];
#pragma unroll
  for (int g = 0; g < 4; ++g)
#pragma unroll
    for (int dc = 0; dc < 2; ++dc) {
      const float* src = Qp + (size_t)(q0w + g * 16 + l15) * DD + dc * 32 + quad * 8;
      float4 a = *(const float4*)src;
      float4 c = *(const float4*)(src + 4);
      U8 t;
      t.u[0] = pk_rne(a.x * QS, a.y * QS); t.u[1] = pk_rne(a.z * QS, a.w * QS);
      t.u[2] = pk_rne(c.x * QS, c.y * QS); t.u[3] = pk_rne(c.z * QS, c.w * QS);
      qf[g][dc] = t.s;
    }
  f32x4 o[4][4]; f32x4 osum[4];
#pragma unroll
  for (int g = 0; g < 4; ++g) {
#pragma unroll
    for (int dc = 0; dc < 4; ++dc) o[g][dc] = (f32x4){0.f, 0.f, 0.f, 0.f};
    osum[g] = (f32x4){0.f, 0.f, 0.f, 0.f};
  }
  const int kr = lane, kcb = wv * 16;
  const int vr2 = (lane & 31) * 2, vcb = wv * 16 + (lane >> 5) * 8;
  const float* kbase = Kp + (size_t)kr * DD + kcb;
  const float* vbase = Vp + (size_t)vr2 * DD + vcb;
  float4 kA, kB, kC, kD, vA, vB, vC, vD;
  uint2 mwc[4], mwn[4];
  {
    const float4* kp = (const float4*)kbase;
    kA = kp[0]; kB = kp[1]; kC = kp[2]; kD = kp[3];
    const float* r0 = vbase;
    vA = ((const float4*)r0)[0]; vB = ((const float4*)r0)[1];
    vC = ((const float4*)(r0 + DD))[0]; vD = ((const float4*)(r0 + DD))[1];
    if (USE_BITS) {
#pragma unroll
      for (int g = 0; g < 4; ++g)
        mwc[g] = *(const uint2*)&bits[(size_t)(brow + q0w + g * 16 + l15) * (SQ / 32)];
    }
    U8 w0, w1;
    w0.u[0] = pk_rne(kA.x, kA.y); w0.u[1] = pk_rne(kA.z, kA.w);
    w0.u[2] = pk_rne(kB.x, kB.y); w0.u[3] = pk_rne(kB.z, kB.w);
    w1.u[0] = pk_rne(kC.x, kC.y); w1.u[1] = pk_rne(kC.z, kC.w);
    w1.u[2] = pk_rne(kD.x, kD.y); w1.u[3] = pk_rne(kD.z, kD.w);
    *(short8*)&sK[0][kr * 72 + kcb] = w0.s;
    *(short8*)&sK[0][kr * 72 + kcb + 8] = w1.s;
    float av[8] = {vA.x, vA.y, vA.z, vA.w, vB.x, vB.y, vB.z, vB.w};
    float bv[8] = {vC.x, vC.y, vC.z, vC.w, vD.x, vD.y, vD.z, vD.w};
#pragma unroll
    for (int j = 0; j < 8; ++j)
      *(uint32_t*)&sVT[0][(vcb + j) * 72 + vr2] = pk_rne(av[j], bv[j]);
  }
  for (int kt = 0; kt < SQ / 64; ++kt) {
    const int buf = kt & 1;
    const int k0 = kt * 64;
    __syncthreads();
    if (kt + 1 < SQ / 64) {
      const float4* kp = (const float4*)(kbase + (size_t)(k0 + 64) * DD);
      kA = kp[0]; kB = kp[1]; kC = kp[2]; kD = kp[3];
      const float* r0 = vbase + (size_t)(k0 + 64) * DD;
      vA = ((const float4*)r0)[0]; vB = ((const float4*)r0)[1];
      vC = ((const float4*)(r0 + DD))[0]; vD = ((const float4*)(r0 + DD))[1];
      if (USE_BITS) {
#pragma unroll
        for (int g = 0; g < 4; ++g)
          mwn[g] = *(const uint2*)&bits[(size_t)(brow + q0w + g * 16 + l15) * (SQ / 32) + (kt + 1) * 2];
      }
    }
    const short* sKb = sK[buf];
    const short* sVb = sVT[buf];
#pragma unroll
    for (int kb = 0; kb < 4; ++kb) {
      short8 kfa = *(const short8*)&sKb[(kb * 16 + l15) * 72 + quad * 8];
      short8 kfb = *(const short8*)&sKb[(kb * 16 + l15) * 72 + 32 + quad * 8];
      bshort4 vf[4];
#pragma unroll
      for (int dc = 0; dc < 4; ++dc)
        vf[dc] = *(const bshort4*)&sVb[(dc * 16 + l15) * 72 + kb * 16 + quad * 4];
#pragma unroll
      for (int g = 0; g < 4; ++g) {
        uint32_t t;
        if (USE_BITS) {
          uint32_t w = (kb & 2) ? mwc[g].y : mwc[g].x;
          t = w >> ((kb & 1) * 16 + quad * 4);
        } else {
          const int* mrow = Mg + (size_t)(brow + q0w + g * 16 + l15) * SQ + k0 + kb * 16 + quad * 4;
          t = (mrow[0] != 0) | ((mrow[1] != 0) << 1) | ((mrow[2] != 0) << 2) |
              ((mrow[3] != 0) << 3);
        }
        f32x4 ci;
        ci[0] = (t & 1) ? NC : NINF;
        ci[1] = (t & 2) ? NC : NINF;
        ci[2] = (t & 4) ? NC : NINF;
        ci[3] = (t & 8) ? NC : NINF;
        f32x4 st = mfma32(kfa, qf[g][0], ci);
        st = mfma32(kfb, qf[g][1], st);
        float p0 = EXP2(st[0]), p1 = EXP2(st[1]), p2 = EXP2(st[2]), p3 = EXP2(st[3]);
        U4 pw;
        pw.u[0] = pk_tr(p0, p1);
        pw.u[1] = pk_tr(p2, p3);
#pragma unroll
        for (int dc = 0; dc < 4; ++dc)
          o[g][dc] = mfma16(pw.s, vf[dc], o[g][dc]);
        osum[g] = mfma16(pw.s, ones, osum[g]);
      }
    }
    if (kt + 1 < SQ / 64) {
      short* dK = (short*)sK[buf ^ 1];
      short* dV = (short*)sVT[buf ^ 1];
      U8 w0, w1;
      w0.u[0] = pk_rne(kA.x, kA.y); w0.u[1] = pk_rne(kA.z, kA.w);
      w0.u[2] = pk_rne(kB.x, kB.y); w0.u[3] = pk_rne(kB.z, kB.w);
      w1.u[0] = pk_rne(kC.x, kC.y); w1.u[1] = pk_rne(kC.z, kC.w);
      w1.u[2] = pk_rne(kD.x, kD.y); w1.u[3] = pk_rne(kD.z, kD.w);
      *(short8*)&dK[kr * 72 + kcb] = w0.s;
      *(short8*)&dK[kr * 72 + kcb + 8] = w1.s;
      float av[8] = {vA.x, vA.y, vA.z, vA.w, vB.x, vB.y, vB.z, vB.w};
      float bv[8] = {vC.x, vC.y, vC.z, vC.w, vD.x, vD.y, vD.z, vD.w};
#pragma unroll
      for (int j = 0; j < 8; ++j)
        *(uint32_t*)&dV[(vcb + j) * 72 + vr2] = pk_rne(av[j], bv[j]);
      if (USE_BITS) {
#pragma unroll
        for (int g = 0; g < 4; ++g) mwc[g] = mwn[g];
      }
    }
  }
#pragma unroll
  for (int g = 0; g < 4; ++g)
#pragma unroll
    for (int r = 0; r < 4; ++r) {
      float inv = 1.0f / osum[g][r];
      float* dst = Op + (size_t)(q0w + g * 16 + quad * 4 + r) * DD + l15;
      dst[0]  = o[g][0][r] * inv;
      dst[16] = o[g][1][r] * inv;
      dst[32] = o[g][2][r] * inv;
      dst[48] = o[g][3][r] * inv;
    }
}

extern "C" void kernel_launch(void* const* d_in, const int* in_sizes, int n_in,
                              void* d_out, int out_size, void* d_ws, size_t ws_size,
                              hipStream_t stream) {
  const float* Q = (const float*)d_in[0];
  const float* K = (const float*)d_in[1];
  const float* V = (const float*)d_in[2];
  const int* M = (const int*)d_in[3];
  float* out = (float*)d_out;

  const size_t bits_bytes = (size_t)4 * SQ * SQ / 8;          // 2 MB
  const size_t kv_bytes = (size_t)64 * SQ * DD * 2;           // 16.78 MB each
  const size_t full_bytes = bits_bytes + 2 * kv_bytes;        // 35.65 MB

  if (ws_size >= full_bytes) {
    uint32_t* bits = (uint32_t*)d_ws;
    short* Kt = (short*)((char*)d_ws + bits_bytes);
    short* Vt = (short*)((char*)d_ws + bits_bytes + kv_bytes);
    prep_all_kernel<<<6144, 256, 0, stream>>>(K, V, M, Kt, Vt, bits);
    attn_fast<<<4 * (SQ / 128) * 16, 256, 0, stream>>>(Q, Kt, Vt, bits, out);  // 1024
  } else if (ws_size >= bits_bytes) {
    uint32_t* bits = (uint32_t*)d_ws;
    pack_mask_kernel<<<2048, 256, 0, stream>>>(M, bits);
    attn_fb<true><<<4 * (SQ / 256) * 16, 256, 0, stream>>>(Q, K, V, M, bits, out);
  } else {
    attn_fb<false><<<4 * (SQ / 256) * 16, 256, 0, stream>>>(Q, K, V, M, nullptr, out);
  }
}